// Round 1
// baseline (3275.621 us; speedup 1.0000x reference)
//
#include <hip/hip_runtime.h>

#define NN 100000
#define En 400000
#define Gn 2000

typedef unsigned short u16;
typedef unsigned int u32;
typedef __bf16 bf16x8 __attribute__((ext_vector_type(8)));
typedef float f32x4 __attribute__((ext_vector_type(4)));

__device__ __forceinline__ u16 f2bf(float f) {
  union { float f; u32 u; } v; v.f = f;
  return (u16)((v.u + 0x7FFFu + ((v.u >> 16) & 1u)) >> 16);
}
__device__ __forceinline__ float bf2f(u16 h) {
  union { u32 u; float f; } v; v.u = ((u32)h) << 16;
  return v.f;
}
__device__ __forceinline__ float fast_tanh(float x) {
  x = fminf(15.f, fmaxf(-15.f, x));
  float e = __expf(2.f * x);
  return (e - 1.f) / (e + 1.f);
}

#define MFMA16(a, b, c) __builtin_amdgcn_mfma_f32_16x16x32_bf16(a, b, c, 0, 0, 0)

// ---------------- prep kernels ----------------

__global__ __launch_bounds__(256) void k_convert(const float* __restrict__ src,
                                                 u16* __restrict__ dst, int n) {
  int i = blockIdx.x * 256 + threadIdx.x;
  if (i < n) dst[i] = f2bf(src[i]);
}

// We2 [3][128][428] -> bf16 padded [3][128][448]
__global__ __launch_bounds__(256) void k_pad_we2(const float* __restrict__ We2,
                                                 u16* __restrict__ dst) {
  int i = blockIdx.x * 256 + threadIdx.x;
  if (i >= 3 * 128 * 448) return;
  int l = i / 57344;
  int r = i - l * 57344;
  int row = r / 448;
  int k = r - row * 448;
  float v = (k < 428) ? We2[l * 54784 + row * 428 + k] : 0.f;
  dst[i] = f2bf(v);
}

// R = We1[:, :, 128:] [3][428][300] -> bf16 padded [3][448][320]
__global__ __launch_bounds__(256) void k_pad_R(const float* __restrict__ We1,
                                               u16* __restrict__ dst) {
  int i = blockIdx.x * 256 + threadIdx.x;
  if (i >= 3 * 448 * 320) return;
  int l = i / 143360;
  int r = i - l * 143360;
  int row = r / 320;
  int k = r - row * 320;
  float v = 0.f;
  if (row < 428 && k < 300) v = We1[(size_t)l * 183184 + row * 428 + 128 + k];
  dst[i] = f2bf(v);
}

// T1[l][t][j] = sum_d edge_emb[t][d] * We1[l][j][d], stored stride 432
__global__ __launch_bounds__(256) void k_t1(const float* __restrict__ edge_emb,
                                            const float* __restrict__ We1,
                                            float* __restrict__ T1) {
  int idx = blockIdx.x * 256 + threadIdx.x;
  if (idx >= 3 * 400 * 428) return;
  int l = idx / (400 * 428);
  int r = idx - l * (400 * 428);
  int t = r / 428;
  int j = r - t * 428;
  const float4* er = (const float4*)(edge_emb + t * 128);
  const float4* wr = (const float4*)(We1 + (size_t)l * 183184 + j * 428);
  float s = 0.f;
#pragma unroll
  for (int d = 0; d < 32; ++d) {
    float4 a = er[d], b = wr[d];
    s += a.x * b.x + a.y * b.y + a.z * b.z + a.w * b.w;
  }
  T1[l * 172800 + t * 432 + j] = s;
}

// h[n][:] = node_emb[Z[n]][:]  (float4 per thread)
__global__ __launch_bounds__(256) void k_hinit(const int* __restrict__ Z,
                                               const float* __restrict__ node_emb,
                                               float* __restrict__ h) {
  int idx = blockIdx.x * 256 + threadIdx.x;  // < N*32
  int n = idx >> 5;
  int c = idx & 31;
  ((float4*)h)[idx] = ((const float4*)node_emb)[Z[n] * 32 + c];
}

__global__ __launch_bounds__(256) void k_zero_out(float* __restrict__ out) {
  int i = blockIdx.x * 256 + threadIdx.x;
  if (i < Gn) out[i] = 0.f;
}

// ---------------- node MLP: n2 = relu(h@W1^T+b1)@W2^T+b2  (bf16 out) ----------------

__global__ __launch_bounds__(256) void k_node(const float* __restrict__ h,
                                              const u16* __restrict__ W1,
                                              const float* __restrict__ b1,
                                              const u16* __restrict__ W2,
                                              const float* __restrict__ b2,
                                              u16* __restrict__ n2) {
  __shared__ __align__(16) u16 sH[64 * 136];
  __shared__ __align__(16) u16 sT[64 * 136];
  const int tid = threadIdx.x;
  const int nbase = blockIdx.x * 64;
  for (int i = tid; i < 64 * 128; i += 256) {
    int e = i >> 7, d = i & 127;
    int node = nbase + e;
    float v = (node < NN) ? h[(size_t)node * 128 + d] : 0.f;
    sH[e * 136 + d] = f2bf(v);
  }
  __syncthreads();
  const int lane = tid & 63, wave = tid >> 6;
  const int q = lane >> 4, ln = lane & 15;
  const int nb = wave * 32;

  f32x4 acc[4][2];
#pragma unroll
  for (int m = 0; m < 4; ++m)
#pragma unroll
    for (int n = 0; n < 2; ++n) acc[m][n] = 0.f;
#pragma unroll
  for (int k0 = 0; k0 < 128; k0 += 32) {
    bf16x8 a[4];
#pragma unroll
    for (int m = 0; m < 4; ++m)
      a[m] = *(const bf16x8*)&sH[(m * 16 + ln) * 136 + k0 + q * 8];
#pragma unroll
    for (int n = 0; n < 2; ++n) {
      bf16x8 b = *(const bf16x8*)&W1[(nb + n * 16 + ln) * 128 + k0 + q * 8];
#pragma unroll
      for (int m = 0; m < 4; ++m) acc[m][n] = MFMA16(a[m], b, acc[m][n]);
    }
  }
#pragma unroll
  for (int n = 0; n < 2; ++n) {
    int col = nb + n * 16 + ln;
    float bb = b1[col];
#pragma unroll
    for (int m = 0; m < 4; ++m)
#pragma unroll
      for (int r = 0; r < 4; ++r) {
        int row = m * 16 + q * 4 + r;
        sT[row * 136 + col] = f2bf(fmaxf(acc[m][n][r] + bb, 0.f));
      }
  }
  __syncthreads();

  f32x4 acc2[4][2];
#pragma unroll
  for (int m = 0; m < 4; ++m)
#pragma unroll
    for (int n = 0; n < 2; ++n) acc2[m][n] = 0.f;
#pragma unroll
  for (int k0 = 0; k0 < 128; k0 += 32) {
    bf16x8 a[4];
#pragma unroll
    for (int m = 0; m < 4; ++m)
      a[m] = *(const bf16x8*)&sT[(m * 16 + ln) * 136 + k0 + q * 8];
#pragma unroll
    for (int n = 0; n < 2; ++n) {
      bf16x8 b = *(const bf16x8*)&W2[(nb + n * 16 + ln) * 128 + k0 + q * 8];
#pragma unroll
      for (int m = 0; m < 4; ++m) acc2[m][n] = MFMA16(a[m], b, acc2[m][n]);
    }
  }
#pragma unroll
  for (int n = 0; n < 2; ++n) {
    int col = nb + n * 16 + ln;
    float bb = b2[col];
#pragma unroll
    for (int m = 0; m < 4; ++m)
#pragma unroll
      for (int r = 0; r < 4; ++r) {
        int row = m * 16 + q * 4 + r;
        int node = nbase + row;
        if (node < NN) n2[(size_t)node * 128 + col] = f2bf(acc2[m][n][r] + bb);
      }
  }
}

// ---------------- fused edge kernel (one layer) ----------------

__global__ __launch_bounds__(256) void k_edge(
    const int* __restrict__ etype, const float* __restrict__ dist,
    const int* __restrict__ src, const int* __restrict__ dstv,
    const float* __restrict__ T1, const float* __restrict__ be1,
    const u16* __restrict__ Rb, const u16* __restrict__ We2b,
    const float* __restrict__ be2, const u16* __restrict__ Wcb,
    const float* __restrict__ bc, const u16* __restrict__ n2,
    float* __restrict__ h) {
  __shared__ __align__(16) u16 sU[64 * 456];   // U = relu(...)  [64][448] pad 456
  __shared__ __align__(16) u16 sA[64 * 328];   // RBF [64][320] pad 328; reused as P [64][136]
  __shared__ int sSrc[64], sDst[64], sEt[64];
  __shared__ float sDist[64];

  const int tid = threadIdx.x;
  const int e0 = blockIdx.x * 64;
  if (tid < 64) {
    sSrc[tid] = src[e0 + tid];
    sDst[tid] = dstv[e0 + tid];
    sEt[tid] = etype[e0 + tid];
    sDist[tid] = dist[e0 + tid];
  }
  __syncthreads();

  // RBF features, bf16, zero-padded K 300->320
  for (int i = tid; i < 64 * 320; i += 256) {
    int e = i / 320;
    int k = i - e * 320;
    float v = 0.f;
    if (k < 300) {
      float x = sDist[e] - (float)k * (30.f / 299.f);
      v = __expf(-x * x * (299.f / 30.f));
    }
    sA[e * 328 + k] = f2bf(v);
  }
  __syncthreads();

  const int lane = tid & 63, wave = tid >> 6;
  const int q = lane >> 4, ln = lane & 15;

  // phase 1: U = relu(RBF @ R^T + T1[et] + be1)  -> sU [64][448]
  {
    f32x4 acc[4][7];
#pragma unroll
    for (int m = 0; m < 4; ++m)
#pragma unroll
      for (int n = 0; n < 7; ++n) acc[m][n] = 0.f;
    const int nb = wave * 112;
    for (int k0 = 0; k0 < 320; k0 += 32) {
      bf16x8 a[4];
#pragma unroll
      for (int m = 0; m < 4; ++m)
        a[m] = *(const bf16x8*)&sA[(m * 16 + ln) * 328 + k0 + q * 8];
#pragma unroll
      for (int n = 0; n < 7; ++n) {
        bf16x8 b = *(const bf16x8*)&Rb[(nb + n * 16 + ln) * 320 + k0 + q * 8];
#pragma unroll
        for (int m = 0; m < 4; ++m) acc[m][n] = MFMA16(a[m], b, acc[m][n]);
      }
    }
#pragma unroll
    for (int n = 0; n < 7; ++n) {
      int col = nb + n * 16 + ln;
      float bb = (col < 428) ? be1[col] : 0.f;
#pragma unroll
      for (int m = 0; m < 4; ++m)
#pragma unroll
        for (int r = 0; r < 4; ++r) {
          int row = m * 16 + q * 4 + r;
          float v = 0.f;
          if (col < 428)
            v = fmaxf(acc[m][n][r] + T1[sEt[row] * 432 + col] + bb, 0.f);
          sU[row * 456 + col] = f2bf(v);
        }
    }
  }
  __syncthreads();

  // phase 2: EE = U @ We2^T + be2 ;  P = EE * n2[src]  -> sP [64][128] (alias of sA)
  u16* sP = sA;
  {
    f32x4 acc[4][2];
#pragma unroll
    for (int m = 0; m < 4; ++m)
#pragma unroll
      for (int n = 0; n < 2; ++n) acc[m][n] = 0.f;
    const int nb = wave * 32;
    for (int k0 = 0; k0 < 448; k0 += 32) {
      bf16x8 a[4];
#pragma unroll
      for (int m = 0; m < 4; ++m)
        a[m] = *(const bf16x8*)&sU[(m * 16 + ln) * 456 + k0 + q * 8];
#pragma unroll
      for (int n = 0; n < 2; ++n) {
        bf16x8 b = *(const bf16x8*)&We2b[(nb + n * 16 + ln) * 448 + k0 + q * 8];
#pragma unroll
        for (int m = 0; m < 4; ++m) acc[m][n] = MFMA16(a[m], b, acc[m][n]);
      }
    }
#pragma unroll
    for (int n = 0; n < 2; ++n) {
      int col = nb + n * 16 + ln;
      float bb = be2[col];
#pragma unroll
      for (int m = 0; m < 4; ++m)
#pragma unroll
        for (int r = 0; r < 4; ++r) {
          int row = m * 16 + q * 4 + r;
          float ee = acc[m][n][r] + bb;
          float nn = bf2f(n2[(size_t)sSrc[row] * 128 + col]);
          sP[row * 136 + col] = f2bf(ee * nn);
        }
    }
  }
  __syncthreads();

  // phase 3: m = tanh(P @ Wc^T + bc); h[dst] += m  (atomic)
  {
    f32x4 acc[4][2];
#pragma unroll
    for (int m = 0; m < 4; ++m)
#pragma unroll
      for (int n = 0; n < 2; ++n) acc[m][n] = 0.f;
    const int nb = wave * 32;
#pragma unroll
    for (int k0 = 0; k0 < 128; k0 += 32) {
      bf16x8 a[4];
#pragma unroll
      for (int m = 0; m < 4; ++m)
        a[m] = *(const bf16x8*)&sP[(m * 16 + ln) * 136 + k0 + q * 8];
#pragma unroll
      for (int n = 0; n < 2; ++n) {
        bf16x8 b = *(const bf16x8*)&Wcb[(nb + n * 16 + ln) * 128 + k0 + q * 8];
#pragma unroll
        for (int m = 0; m < 4; ++m) acc[m][n] = MFMA16(a[m], b, acc[m][n]);
      }
    }
#pragma unroll
    for (int n = 0; n < 2; ++n) {
      int col = nb + n * 16 + ln;
      float bb = bc[col];
#pragma unroll
      for (int m = 0; m < 4; ++m)
#pragma unroll
        for (int r = 0; r < 4; ++r) {
          int row = m * 16 + q * 4 + r;
          float t = fast_tanh(acc[m][n][r] + bb);
          unsafeAtomicAdd(&h[(size_t)sDst[row] * 128 + col], t);
        }
    }
  }
}

// ---------------- readout: out[g] += relu(h@Wr1^T+br1)@Wr2^T + br2 ----------------

__global__ __launch_bounds__(256) void k_read(const float* __restrict__ h,
                                              const float* __restrict__ Wr1,
                                              const float* __restrict__ br1,
                                              const float* __restrict__ Wr2,
                                              const float* __restrict__ br2,
                                              const int* __restrict__ gid,
                                              float* __restrict__ out) {
  __shared__ __align__(16) u16 sH[64 * 136];
  __shared__ __align__(16) u16 sW[128 * 136];
  __shared__ float sR4[4][64];
  const int tid = threadIdx.x;
  const int nbase = blockIdx.x * 64;
  for (int i = tid; i < 64 * 128; i += 256) {
    int e = i >> 7, d = i & 127;
    int node = nbase + e;
    float v = (node < NN) ? h[(size_t)node * 128 + d] : 0.f;
    sH[e * 136 + d] = f2bf(v);
  }
  for (int i = tid; i < 128 * 128; i += 256) {
    int rr = i >> 7, d = i & 127;
    sW[rr * 136 + d] = f2bf(Wr1[i]);
  }
  __syncthreads();
  const int lane = tid & 63, wave = tid >> 6;
  const int q = lane >> 4, ln = lane & 15;
  const int nb = wave * 32;

  f32x4 acc[4][2];
#pragma unroll
  for (int m = 0; m < 4; ++m)
#pragma unroll
    for (int n = 0; n < 2; ++n) acc[m][n] = 0.f;
#pragma unroll
  for (int k0 = 0; k0 < 128; k0 += 32) {
    bf16x8 a[4];
#pragma unroll
    for (int m = 0; m < 4; ++m)
      a[m] = *(const bf16x8*)&sH[(m * 16 + ln) * 136 + k0 + q * 8];
#pragma unroll
    for (int n = 0; n < 2; ++n) {
      bf16x8 b = *(const bf16x8*)&sW[(nb + n * 16 + ln) * 136 + k0 + q * 8];
#pragma unroll
      for (int m = 0; m < 4; ++m) acc[m][n] = MFMA16(a[m], b, acc[m][n]);
    }
  }
#pragma unroll
  for (int m = 0; m < 4; ++m)
#pragma unroll
    for (int r = 0; r < 4; ++r) {
      float t = 0.f;
#pragma unroll
      for (int n = 0; n < 2; ++n) {
        int col = nb + n * 16 + ln;
        t += fmaxf(acc[m][n][r] + br1[col], 0.f) * Wr2[col];
      }
      t += __shfl_xor(t, 1);
      t += __shfl_xor(t, 2);
      t += __shfl_xor(t, 4);
      t += __shfl_xor(t, 8);
      if (ln == 0) sR4[wave][m * 16 + q * 4 + r] = t;
    }
  __syncthreads();
  if (tid < 64) {
    int node = nbase + tid;
    if (node < NN) {
      float s = sR4[0][tid] + sR4[1][tid] + sR4[2][tid] + sR4[3][tid] + br2[0];
      unsafeAtomicAdd(&out[gid[node]], s);
    }
  }
}

// ---------------- launch ----------------

extern "C" void kernel_launch(void* const* d_in, const int* in_sizes, int n_in,
                              void* d_out, int out_size, void* d_ws, size_t ws_size,
                              hipStream_t stream) {
  const int* Z = (const int*)d_in[0];
  const int* etype = (const int*)d_in[1];
  const float* dist = (const float*)d_in[2];
  const int* src = (const int*)d_in[3];
  const int* dst = (const int*)d_in[4];
  const int* gid = (const int*)d_in[5];
  const float* node_emb = (const float*)d_in[6];
  const float* edge_emb = (const float*)d_in[7];
  const float* Wn1 = (const float*)d_in[8];
  const float* bn1 = (const float*)d_in[9];
  const float* Wn2 = (const float*)d_in[10];
  const float* bn2 = (const float*)d_in[11];
  const float* We1 = (const float*)d_in[12];
  const float* be1 = (const float*)d_in[13];
  const float* We2 = (const float*)d_in[14];
  const float* be2 = (const float*)d_in[15];
  const float* Wc = (const float*)d_in[16];
  const float* bc = (const float*)d_in[17];
  const float* Wr1 = (const float*)d_in[18];
  const float* br1 = (const float*)d_in[19];
  const float* Wr2 = (const float*)d_in[20];
  const float* br2 = (const float*)d_in[21];
  float* out = (float*)d_out;

  char* ws = (char*)d_ws;
  float* h = (float*)(ws);                   // [N][128] f32      51,200,000 B
  u16* n2 = (u16*)(ws + 51200000);           // [N][128] bf16     25,600,000 B
  u16* Rb = (u16*)(ws + 76800000);           // [3][448][320]        860,160 B
  u16* We2b = (u16*)(ws + 77660160);         // [3][128][448]        344,064 B
  u16* Wcb = (u16*)(ws + 78004224);          // [3][128][128]         98,304 B
  u16* Wn1b = (u16*)(ws + 78102528);         //                       98,304 B
  u16* Wn2b = (u16*)(ws + 78200832);         //                       98,304 B
  float* T1 = (float*)(ws + 78299136);       // [3][400][432] f32  2,073,600 B  (end 80,372,736)

  k_convert<<<192, 256, 0, stream>>>(Wn1, Wn1b, 49152);
  k_convert<<<192, 256, 0, stream>>>(Wn2, Wn2b, 49152);
  k_convert<<<192, 256, 0, stream>>>(Wc, Wcb, 49152);
  k_pad_we2<<<672, 256, 0, stream>>>(We2, We2b);
  k_pad_R<<<1680, 256, 0, stream>>>(We1, Rb);
  k_t1<<<2007, 256, 0, stream>>>(edge_emb, We1, T1);
  k_hinit<<<12500, 256, 0, stream>>>(Z, node_emb, h);
  k_zero_out<<<8, 256, 0, stream>>>(out);

  for (int l = 0; l < 3; ++l) {
    k_node<<<1563, 256, 0, stream>>>(h, Wn1b + l * 16384, bn1 + l * 128,
                                     Wn2b + l * 16384, bn2 + l * 128, n2);
    k_edge<<<6250, 256, 0, stream>>>(etype, dist, src, dst,
                                     T1 + l * 172800, be1 + l * 428,
                                     Rb + l * 143360, We2b + l * 57344,
                                     be2 + l * 128, Wcb + l * 16384,
                                     bc + l * 128, n2, h);
  }
  k_read<<<1563, 256, 0, stream>>>(h, Wr1, br1, Wr2, br2, gid, out);
}

// Round 2
// 1173.102 us; speedup vs baseline: 2.7923x; 2.7923x over previous
//
#include <hip/hip_runtime.h>

#define NN 100000
#define En 400000
#define Gn 2000
#define GRID 2048

typedef unsigned short u16;
typedef unsigned int u32;
typedef __bf16 bf16x8 __attribute__((ext_vector_type(8)));
typedef float f32x4 __attribute__((ext_vector_type(4)));

__device__ __forceinline__ u16 f2bf(float f) {
  union { float f; u32 u; } v; v.f = f;
  return (u16)((v.u + 0x7FFFu + ((v.u >> 16) & 1u)) >> 16);
}
__device__ __forceinline__ float bf2f(u16 h) {
  union { u32 u; float f; } v; v.u = ((u32)h) << 16;
  return v.f;
}
__device__ __forceinline__ float fast_tanh(float x) {
  x = fminf(15.f, fmaxf(-15.f, x));
  float e = __expf(2.f * x);
  return (e - 1.f) / (e + 1.f);
}

#define MFMA16(a, b, c) __builtin_amdgcn_mfma_f32_16x16x32_bf16(a, b, c, 0, 0, 0)

// ---------------- prep kernels ----------------

__global__ __launch_bounds__(256) void k_convert(const float* __restrict__ src,
                                                 u16* __restrict__ dst, int n) {
  int i = blockIdx.x * 256 + threadIdx.x;
  if (i < n) dst[i] = f2bf(src[i]);
}

// We2 [3][128][428] -> bf16 padded [3][128][448]
__global__ __launch_bounds__(256) void k_pad_we2(const float* __restrict__ We2,
                                                 u16* __restrict__ dst) {
  int i = blockIdx.x * 256 + threadIdx.x;
  if (i >= 3 * 128 * 448) return;
  int l = i / 57344;
  int r = i - l * 57344;
  int row = r / 448;
  int k = r - row * 448;
  float v = (k < 428) ? We2[l * 54784 + row * 428 + k] : 0.f;
  dst[i] = f2bf(v);
}

// R = We1[:, :, 128:] [3][428][300] -> bf16 padded [3][448][320]
__global__ __launch_bounds__(256) void k_pad_R(const float* __restrict__ We1,
                                               u16* __restrict__ dst) {
  int i = blockIdx.x * 256 + threadIdx.x;
  if (i >= 3 * 448 * 320) return;
  int l = i / 143360;
  int r = i - l * 143360;
  int row = r / 320;
  int k = r - row * 320;
  float v = 0.f;
  if (row < 428 && k < 300) v = We1[(size_t)l * 183184 + row * 428 + 128 + k];
  dst[i] = f2bf(v);
}

// T2[l][t][j] = edge_emb[t]·We1[l][j][:128] + be1[l][j]   bf16 [3][400][448]
__global__ __launch_bounds__(256) void k_t2(const float* __restrict__ edge_emb,
                                            const float* __restrict__ We1,
                                            const float* __restrict__ be1,
                                            u16* __restrict__ T2) {
  int idx = blockIdx.x * 256 + threadIdx.x;
  if (idx >= 3 * 400 * 448) return;
  int l = idx / (400 * 448);
  int r = idx - l * (400 * 448);
  int t = r / 448;
  int j = r - t * 448;
  float s = 0.f;
  if (j < 428) {
    const float4* er = (const float4*)(edge_emb + t * 128);
    const float4* wr = (const float4*)(We1 + (size_t)l * 183184 + j * 428);
#pragma unroll
    for (int d = 0; d < 32; ++d) {
      float4 a = er[d], b = wr[d];
      s += a.x * b.x + a.y * b.y + a.z * b.z + a.w * b.w;
    }
    s += be1[l * 428 + j];
  }
  T2[idx] = f2bf(s);
}

// Dtab[l][g][j] = sum_k rbf_k(g*delta) * R[l][j][k]   bf16 [3][GRID+1][448]
// windowed to 32 centers (exp(-25.7) ~ 7e-12 outside)
__global__ __launch_bounds__(256) void k_dtab(const u16* __restrict__ Rb,
                                              u16* __restrict__ Dtab) {
  const int tid = threadIdx.x;
  int l = blockIdx.x / (GRID + 1);
  int g = blockIdx.x - l * (GRID + 1);
  float d = (float)g * (30.f / (float)GRID);
  int kc = (int)(d * (299.f / 30.f) + 0.5f);
  int kk0 = min(max(kc - 16, 0), 268);
  __shared__ float sE[32];
  if (tid < 32) {
    float x = d - (float)(kk0 + tid) * (30.f / 299.f);
    sE[tid] = __expf(-x * x * (299.f / 30.f));
  }
  __syncthreads();
  for (int j = tid; j < 448; j += 256) {
    const u16* rr = &Rb[((size_t)l * 448 + j) * 320 + kk0];
    float s = 0.f;
#pragma unroll
    for (int k = 0; k < 32; ++k) s += sE[k] * bf2f(rr[k]);
    Dtab[((size_t)(l * (GRID + 1) + g)) * 448 + j] = f2bf(s);
  }
}

// h[n][:] = node_emb[Z[n]][:]
__global__ __launch_bounds__(256) void k_hinit(const int* __restrict__ Z,
                                               const float* __restrict__ node_emb,
                                               float* __restrict__ h) {
  int idx = blockIdx.x * 256 + threadIdx.x;
  int n = idx >> 5;
  int c = idx & 31;
  ((float4*)h)[idx] = ((const float4*)node_emb)[Z[n] * 32 + c];
}

__global__ __launch_bounds__(256) void k_zero_out(float* __restrict__ out) {
  int i = blockIdx.x * 256 + threadIdx.x;
  if (i < Gn) out[i] = 0.f;
}

// ---------------- node MLP: n2 = relu(h@W1^T+b1)@W2^T+b2  (bf16 out) ----------------

__global__ __launch_bounds__(256) void k_node(const float* __restrict__ h,
                                              const u16* __restrict__ W1,
                                              const float* __restrict__ b1,
                                              const u16* __restrict__ W2,
                                              const float* __restrict__ b2,
                                              u16* __restrict__ n2) {
  __shared__ __align__(16) u16 sH[64 * 136];
  __shared__ __align__(16) u16 sT[64 * 136];
  const int tid = threadIdx.x;
  const int nbase = blockIdx.x * 64;
  for (int i = tid; i < 64 * 128; i += 256) {
    int e = i >> 7, d = i & 127;
    int node = nbase + e;
    float v = (node < NN) ? h[(size_t)node * 128 + d] : 0.f;
    sH[e * 136 + d] = f2bf(v);
  }
  __syncthreads();
  const int lane = tid & 63, wave = tid >> 6;
  const int q = lane >> 4, ln = lane & 15;
  const int nb = wave * 32;

  f32x4 acc[4][2];
#pragma unroll
  for (int m = 0; m < 4; ++m)
#pragma unroll
    for (int n = 0; n < 2; ++n) acc[m][n] = 0.f;
#pragma unroll
  for (int k0 = 0; k0 < 128; k0 += 32) {
    bf16x8 a[4];
#pragma unroll
    for (int m = 0; m < 4; ++m)
      a[m] = *(const bf16x8*)&sH[(m * 16 + ln) * 136 + k0 + q * 8];
#pragma unroll
    for (int n = 0; n < 2; ++n) {
      bf16x8 b = *(const bf16x8*)&W1[(nb + n * 16 + ln) * 128 + k0 + q * 8];
#pragma unroll
      for (int m = 0; m < 4; ++m) acc[m][n] = MFMA16(a[m], b, acc[m][n]);
    }
  }
#pragma unroll
  for (int n = 0; n < 2; ++n) {
    int col = nb + n * 16 + ln;
    float bb = b1[col];
#pragma unroll
    for (int m = 0; m < 4; ++m)
#pragma unroll
      for (int r = 0; r < 4; ++r) {
        int row = m * 16 + q * 4 + r;
        sT[row * 136 + col] = f2bf(fmaxf(acc[m][n][r] + bb, 0.f));
      }
  }
  __syncthreads();

  f32x4 acc2[4][2];
#pragma unroll
  for (int m = 0; m < 4; ++m)
#pragma unroll
    for (int n = 0; n < 2; ++n) acc2[m][n] = 0.f;
#pragma unroll
  for (int k0 = 0; k0 < 128; k0 += 32) {
    bf16x8 a[4];
#pragma unroll
    for (int m = 0; m < 4; ++m)
      a[m] = *(const bf16x8*)&sT[(m * 16 + ln) * 136 + k0 + q * 8];
#pragma unroll
    for (int n = 0; n < 2; ++n) {
      bf16x8 b = *(const bf16x8*)&W2[(nb + n * 16 + ln) * 128 + k0 + q * 8];
#pragma unroll
      for (int m = 0; m < 4; ++m) acc2[m][n] = MFMA16(a[m], b, acc2[m][n]);
    }
  }
#pragma unroll
  for (int n = 0; n < 2; ++n) {
    int col = nb + n * 16 + ln;
    float bb = b2[col];
#pragma unroll
    for (int m = 0; m < 4; ++m)
#pragma unroll
      for (int r = 0; r < 4; ++r) {
        int row = m * 16 + q * 4 + r;
        int node = nbase + row;
        if (node < NN) n2[(size_t)node * 128 + col] = f2bf(acc2[m][n][r] + bb);
      }
  }
}

// ---------------- fused edge kernel (one layer) ----------------
// LDS ~77 KB -> 2 blocks/CU (8 waves)

__global__ __launch_bounds__(256, 2) void k_edge(
    const int* __restrict__ etype, const float* __restrict__ dist,
    const int* __restrict__ src, const int* __restrict__ dstv,
    const u16* __restrict__ T2, const u16* __restrict__ Dtab,
    const u16* __restrict__ We2b, const float* __restrict__ be2,
    const u16* __restrict__ Wcb, const float* __restrict__ bc,
    const u16* __restrict__ n2, float* __restrict__ h) {
  __shared__ __align__(16) u16 sU[64 * 456];   // U [64][448] pad 456
  __shared__ __align__(16) u16 sP[64 * 136];   // P [64][128] pad 136
  __shared__ int sSrc[64], sDst[64], sT2o[64], sIdx[64];
  __shared__ float sFrac[64];

  const int tid = threadIdx.x;
  const int e0 = blockIdx.x * 64;
  if (tid < 64) {
    int e = e0 + tid;
    sSrc[tid] = src[e];
    sDst[tid] = dstv[e];
    sT2o[tid] = etype[e] * 448;
    float d = dist[e];
    float fi = d * ((float)GRID / 30.f);
    int ix = (int)fi;
    sIdx[tid] = ix * 448;
    sFrac[tid] = fi - (float)ix;
  }
  __syncthreads();

  // phase 1: U = relu(T2[et] + lerp(Dtab[idx], Dtab[idx+1]))  -> sU
  for (int i = tid; i < 64 * 56; i += 256) {
    int e = i / 56;
    int c = (i - e * 56) * 8;
    bf16x8 lo = *(const bf16x8*)&Dtab[sIdx[e] + c];
    bf16x8 hi = *(const bf16x8*)&Dtab[sIdx[e] + 448 + c];
    bf16x8 t2 = *(const bf16x8*)&T2[sT2o[e] + c];
    float fr = sFrac[e];
    bf16x8 o;
#pragma unroll
    for (int j = 0; j < 8; ++j) {
      float l0 = (float)lo[j], h0 = (float)hi[j];
      float v = (float)t2[j] + l0 + fr * (h0 - l0);
      o[j] = (__bf16)fmaxf(v, 0.f);
    }
    *(bf16x8*)&sU[e * 456 + c] = o;
  }
  __syncthreads();

  const int lane = tid & 63, wave = tid >> 6;
  const int q = lane >> 4, ln = lane & 15;

  // phase 2: EE = U @ We2^T + be2 ;  P = EE * n2[src]  -> sP
  {
    f32x4 acc[4][2];
#pragma unroll
    for (int m = 0; m < 4; ++m)
#pragma unroll
      for (int n = 0; n < 2; ++n) acc[m][n] = 0.f;
    const int nb = wave * 32;
    for (int k0 = 0; k0 < 448; k0 += 32) {
      bf16x8 a[4];
#pragma unroll
      for (int m = 0; m < 4; ++m)
        a[m] = *(const bf16x8*)&sU[(m * 16 + ln) * 456 + k0 + q * 8];
#pragma unroll
      for (int n = 0; n < 2; ++n) {
        bf16x8 b = *(const bf16x8*)&We2b[(nb + n * 16 + ln) * 448 + k0 + q * 8];
#pragma unroll
        for (int m = 0; m < 4; ++m) acc[m][n] = MFMA16(a[m], b, acc[m][n]);
      }
    }
#pragma unroll
    for (int n = 0; n < 2; ++n) {
      int col = nb + n * 16 + ln;
      float bb = be2[col];
#pragma unroll
      for (int m = 0; m < 4; ++m)
#pragma unroll
        for (int r = 0; r < 4; ++r) {
          int row = m * 16 + q * 4 + r;
          float ee = acc[m][n][r] + bb;
          float nn = bf2f(n2[(size_t)sSrc[row] * 128 + col]);
          sP[row * 136 + col] = f2bf(ee * nn);
        }
    }
  }
  __syncthreads();

  // phase 3: m = tanh(P @ Wc^T + bc); h[dst] += m  (atomic)
  {
    f32x4 acc[4][2];
#pragma unroll
    for (int m = 0; m < 4; ++m)
#pragma unroll
      for (int n = 0; n < 2; ++n) acc[m][n] = 0.f;
    const int nb = wave * 32;
#pragma unroll
    for (int k0 = 0; k0 < 128; k0 += 32) {
      bf16x8 a[4];
#pragma unroll
      for (int m = 0; m < 4; ++m)
        a[m] = *(const bf16x8*)&sP[(m * 16 + ln) * 136 + k0 + q * 8];
#pragma unroll
      for (int n = 0; n < 2; ++n) {
        bf16x8 b = *(const bf16x8*)&Wcb[(nb + n * 16 + ln) * 128 + k0 + q * 8];
#pragma unroll
        for (int m = 0; m < 4; ++m) acc[m][n] = MFMA16(a[m], b, acc[m][n]);
      }
    }
#pragma unroll
    for (int n = 0; n < 2; ++n) {
      int col = nb + n * 16 + ln;
      float bb = bc[col];
#pragma unroll
      for (int m = 0; m < 4; ++m)
#pragma unroll
        for (int r = 0; r < 4; ++r) {
          int row = m * 16 + q * 4 + r;
          float t = fast_tanh(acc[m][n][r] + bb);
          unsafeAtomicAdd(&h[(size_t)sDst[row] * 128 + col], t);
        }
    }
  }
}

// ---------------- readout ----------------

__global__ __launch_bounds__(256) void k_read(const float* __restrict__ h,
                                              const float* __restrict__ Wr1,
                                              const float* __restrict__ br1,
                                              const float* __restrict__ Wr2,
                                              const float* __restrict__ br2,
                                              const int* __restrict__ gid,
                                              float* __restrict__ out) {
  __shared__ __align__(16) u16 sH[64 * 136];
  __shared__ __align__(16) u16 sW[128 * 136];
  __shared__ float sR4[4][64];
  const int tid = threadIdx.x;
  const int nbase = blockIdx.x * 64;
  for (int i = tid; i < 64 * 128; i += 256) {
    int e = i >> 7, d = i & 127;
    int node = nbase + e;
    float v = (node < NN) ? h[(size_t)node * 128 + d] : 0.f;
    sH[e * 136 + d] = f2bf(v);
  }
  for (int i = tid; i < 128 * 128; i += 256) {
    int rr = i >> 7, d = i & 127;
    sW[rr * 136 + d] = f2bf(Wr1[i]);
  }
  __syncthreads();
  const int lane = tid & 63, wave = tid >> 6;
  const int q = lane >> 4, ln = lane & 15;
  const int nb = wave * 32;

  f32x4 acc[4][2];
#pragma unroll
  for (int m = 0; m < 4; ++m)
#pragma unroll
    for (int n = 0; n < 2; ++n) acc[m][n] = 0.f;
#pragma unroll
  for (int k0 = 0; k0 < 128; k0 += 32) {
    bf16x8 a[4];
#pragma unroll
    for (int m = 0; m < 4; ++m)
      a[m] = *(const bf16x8*)&sH[(m * 16 + ln) * 136 + k0 + q * 8];
#pragma unroll
    for (int n = 0; n < 2; ++n) {
      bf16x8 b = *(const bf16x8*)&sW[(nb + n * 16 + ln) * 136 + k0 + q * 8];
#pragma unroll
      for (int m = 0; m < 4; ++m) acc[m][n] = MFMA16(a[m], b, acc[m][n]);
    }
  }
#pragma unroll
  for (int m = 0; m < 4; ++m)
#pragma unroll
    for (int r = 0; r < 4; ++r) {
      float t = 0.f;
#pragma unroll
      for (int n = 0; n < 2; ++n) {
        int col = nb + n * 16 + ln;
        t += fmaxf(acc[m][n][r] + br1[col], 0.f) * Wr2[col];
      }
      t += __shfl_xor(t, 1);
      t += __shfl_xor(t, 2);
      t += __shfl_xor(t, 4);
      t += __shfl_xor(t, 8);
      if (ln == 0) sR4[wave][m * 16 + q * 4 + r] = t;
    }
  __syncthreads();
  if (tid < 64) {
    int node = nbase + tid;
    if (node < NN) {
      float s = sR4[0][tid] + sR4[1][tid] + sR4[2][tid] + sR4[3][tid] + br2[0];
      unsafeAtomicAdd(&out[gid[node]], s);
    }
  }
}

// ---------------- launch ----------------

extern "C" void kernel_launch(void* const* d_in, const int* in_sizes, int n_in,
                              void* d_out, int out_size, void* d_ws, size_t ws_size,
                              hipStream_t stream) {
  const int* Z = (const int*)d_in[0];
  const int* etype = (const int*)d_in[1];
  const float* dist = (const float*)d_in[2];
  const int* src = (const int*)d_in[3];
  const int* dst = (const int*)d_in[4];
  const int* gid = (const int*)d_in[5];
  const float* node_emb = (const float*)d_in[6];
  const float* edge_emb = (const float*)d_in[7];
  const float* Wn1 = (const float*)d_in[8];
  const float* bn1 = (const float*)d_in[9];
  const float* Wn2 = (const float*)d_in[10];
  const float* bn2 = (const float*)d_in[11];
  const float* We1 = (const float*)d_in[12];
  const float* be1 = (const float*)d_in[13];
  const float* We2 = (const float*)d_in[14];
  const float* be2 = (const float*)d_in[15];
  const float* Wc = (const float*)d_in[16];
  const float* bc = (const float*)d_in[17];
  const float* Wr1 = (const float*)d_in[18];
  const float* br1 = (const float*)d_in[19];
  const float* Wr2 = (const float*)d_in[20];
  const float* br2 = (const float*)d_in[21];
  float* out = (float*)d_out;

  char* ws = (char*)d_ws;
  float* h = (float*)(ws);                   // 51,200,000 B
  u16* n2 = (u16*)(ws + 51200000);           // 25,600,000 B
  u16* Rb = (u16*)(ws + 76800000);           //    860,160 B
  u16* We2b = (u16*)(ws + 77660160);         //    344,064 B
  u16* Wcb = (u16*)(ws + 78004224);          //     98,304 B
  u16* Wn1b = (u16*)(ws + 78102528);         //     98,304 B
  u16* Wn2b = (u16*)(ws + 78200832);         //     98,304 B
  u16* T2 = (u16*)(ws + 78299136);           //  1,075,200 B
  u16* Dtab = (u16*)(ws + 79374336);         //  5,507,712 B  (end 84,882,048)

  k_convert<<<192, 256, 0, stream>>>(Wn1, Wn1b, 49152);
  k_convert<<<192, 256, 0, stream>>>(Wn2, Wn2b, 49152);
  k_convert<<<192, 256, 0, stream>>>(Wc, Wcb, 49152);
  k_pad_we2<<<672, 256, 0, stream>>>(We2, We2b);
  k_pad_R<<<1680, 256, 0, stream>>>(We1, Rb);
  k_t2<<<2100, 256, 0, stream>>>(edge_emb, We1, be1, T2);
  k_dtab<<<3 * (GRID + 1), 256, 0, stream>>>(Rb, Dtab);
  k_hinit<<<12500, 256, 0, stream>>>(Z, node_emb, h);
  k_zero_out<<<8, 256, 0, stream>>>(out);

  for (int l = 0; l < 3; ++l) {
    k_node<<<1563, 256, 0, stream>>>(h, Wn1b + l * 16384, bn1 + l * 128,
                                     Wn2b + l * 16384, bn2 + l * 128, n2);
    k_edge<<<6250, 256, 0, stream>>>(etype, dist, src, dst,
                                     T2 + l * 179200, Dtab + (size_t)l * (GRID + 1) * 448,
                                     We2b + l * 57344, be2 + l * 128,
                                     Wcb + l * 16384, bc + l * 128, n2, h);
  }
  k_read<<<1563, 256, 0, stream>>>(h, Wr1, br1, Wr2, br2, gid, out);
}

// Round 3
// 1064.534 us; speedup vs baseline: 3.0770x; 1.1020x over previous
//
#include <hip/hip_runtime.h>

#define NN 100000
#define En 400000
#define Gn 2000
#define GRID 2048

typedef unsigned short u16;
typedef unsigned int u32;
typedef __bf16 bf16x8 __attribute__((ext_vector_type(8)));
typedef float f32x4 __attribute__((ext_vector_type(4)));

__device__ __forceinline__ u16 f2bf(float f) {
  union { float f; u32 u; } v; v.f = f;
  return (u16)((v.u + 0x7FFFu + ((v.u >> 16) & 1u)) >> 16);
}
__device__ __forceinline__ float bf2f(u16 h) {
  union { u32 u; float f; } v; v.u = ((u32)h) << 16;
  return v.f;
}

// barrier that drains only LDS ops: leaves global loads/atomics in flight
// (safe here: all cross-wave communication in k_edge is through LDS; global
// reads are read-only tables, global atomics are fire-and-forget)
__device__ __forceinline__ void lds_barrier() {
  asm volatile("s_waitcnt lgkmcnt(0)\ns_barrier" ::: "memory");
}

#define MFMA16(a, b, c) __builtin_amdgcn_mfma_f32_16x16x32_bf16(a, b, c, 0, 0, 0)

// ---------------- prep kernels ----------------

__global__ __launch_bounds__(256) void k_convert(const float* __restrict__ src,
                                                 u16* __restrict__ dst, int n) {
  int i = blockIdx.x * 256 + threadIdx.x;
  if (i < n) dst[i] = f2bf(src[i]);
}

// We2 [3][128][428] -> bf16 padded [3][128][448]
__global__ __launch_bounds__(256) void k_pad_we2(const float* __restrict__ We2,
                                                 u16* __restrict__ dst) {
  int i = blockIdx.x * 256 + threadIdx.x;
  if (i >= 3 * 128 * 448) return;
  int l = i / 57344;
  int r = i - l * 57344;
  int row = r / 448;
  int k = r - row * 448;
  float v = (k < 428) ? We2[l * 54784 + row * 428 + k] : 0.f;
  dst[i] = f2bf(v);
}

// R = We1[:, :, 128:] [3][428][300] -> bf16 padded [3][448][320]
__global__ __launch_bounds__(256) void k_pad_R(const float* __restrict__ We1,
                                               u16* __restrict__ dst) {
  int i = blockIdx.x * 256 + threadIdx.x;
  if (i >= 3 * 448 * 320) return;
  int l = i / 143360;
  int r = i - l * 143360;
  int row = r / 320;
  int k = r - row * 320;
  float v = 0.f;
  if (row < 428 && k < 300) v = We1[(size_t)l * 183184 + row * 428 + 128 + k];
  dst[i] = f2bf(v);
}

// T2[l][t][j] = edge_emb[t]·We1[l][j][:128] + be1[l][j]   bf16 [3][400][448]
__global__ __launch_bounds__(256) void k_t2(const float* __restrict__ edge_emb,
                                            const float* __restrict__ We1,
                                            const float* __restrict__ be1,
                                            u16* __restrict__ T2) {
  int idx = blockIdx.x * 256 + threadIdx.x;
  if (idx >= 3 * 400 * 448) return;
  int l = idx / (400 * 448);
  int r = idx - l * (400 * 448);
  int t = r / 448;
  int j = r - t * 448;
  float s = 0.f;
  if (j < 428) {
    const float4* er = (const float4*)(edge_emb + t * 128);
    const float4* wr = (const float4*)(We1 + (size_t)l * 183184 + j * 428);
#pragma unroll
    for (int d = 0; d < 32; ++d) {
      float4 a = er[d], b = wr[d];
      s += a.x * b.x + a.y * b.y + a.z * b.z + a.w * b.w;
    }
    s += be1[l * 428 + j];
  }
  T2[idx] = f2bf(s);
}

// Dtab[l][g][j] = sum_k rbf_k(g*delta) * R[l][j][k]   bf16 [3][GRID+1][448]
__global__ __launch_bounds__(256) void k_dtab(const u16* __restrict__ Rb,
                                              u16* __restrict__ Dtab) {
  const int tid = threadIdx.x;
  int l = blockIdx.x / (GRID + 1);
  int g = blockIdx.x - l * (GRID + 1);
  float d = (float)g * (30.f / (float)GRID);
  int kc = (int)(d * (299.f / 30.f) + 0.5f);
  int kk0 = min(max(kc - 16, 0), 268);
  __shared__ float sE[32];
  if (tid < 32) {
    float x = d - (float)(kk0 + tid) * (30.f / 299.f);
    sE[tid] = __expf(-x * x * (299.f / 30.f));
  }
  __syncthreads();
  for (int j = tid; j < 448; j += 256) {
    const u16* rr = &Rb[((size_t)l * 448 + j) * 320 + kk0];
    float s = 0.f;
#pragma unroll
    for (int k = 0; k < 32; ++k) s += sE[k] * bf2f(rr[k]);
    Dtab[((size_t)(l * (GRID + 1) + g)) * 448 + j] = f2bf(s);
  }
}

// h[n][:] = node_emb[Z[n]][:]
__global__ __launch_bounds__(256) void k_hinit(const int* __restrict__ Z,
                                               const float* __restrict__ node_emb,
                                               float* __restrict__ h) {
  int idx = blockIdx.x * 256 + threadIdx.x;
  int n = idx >> 5;
  int c = idx & 31;
  ((float4*)h)[idx] = ((const float4*)node_emb)[Z[n] * 32 + c];
}

__global__ __launch_bounds__(256) void k_zero_out(float* __restrict__ out) {
  int i = blockIdx.x * 256 + threadIdx.x;
  if (i < Gn) out[i] = 0.f;
}

// ---------------- node MLP: n2 = relu(h@W1^T+b1)@W2^T+b2  (bf16 out) ----------------

__global__ __launch_bounds__(256) void k_node(const float* __restrict__ h,
                                              const u16* __restrict__ W1,
                                              const float* __restrict__ b1,
                                              const u16* __restrict__ W2,
                                              const float* __restrict__ b2,
                                              u16* __restrict__ n2) {
  __shared__ __align__(16) u16 sH[64 * 136];
  __shared__ __align__(16) u16 sT[64 * 136];
  const int tid = threadIdx.x;
  const int nbase = blockIdx.x * 64;
  for (int i = tid; i < 64 * 128; i += 256) {
    int e = i >> 7, d = i & 127;
    int node = nbase + e;
    float v = (node < NN) ? h[(size_t)node * 128 + d] : 0.f;
    sH[e * 136 + d] = f2bf(v);
  }
  __syncthreads();
  const int lane = tid & 63, wave = tid >> 6;
  const int q = lane >> 4, ln = lane & 15;
  const int nb = wave * 32;

  f32x4 acc[4][2];
#pragma unroll
  for (int m = 0; m < 4; ++m)
#pragma unroll
    for (int n = 0; n < 2; ++n) acc[m][n] = 0.f;
#pragma unroll
  for (int k0 = 0; k0 < 128; k0 += 32) {
    bf16x8 a[4];
#pragma unroll
    for (int m = 0; m < 4; ++m)
      a[m] = *(const bf16x8*)&sH[(m * 16 + ln) * 136 + k0 + q * 8];
#pragma unroll
    for (int n = 0; n < 2; ++n) {
      bf16x8 b = *(const bf16x8*)&W1[(nb + n * 16 + ln) * 128 + k0 + q * 8];
#pragma unroll
      for (int m = 0; m < 4; ++m) acc[m][n] = MFMA16(a[m], b, acc[m][n]);
    }
  }
#pragma unroll
  for (int n = 0; n < 2; ++n) {
    int col = nb + n * 16 + ln;
    float bb = b1[col];
#pragma unroll
    for (int m = 0; m < 4; ++m)
#pragma unroll
      for (int r = 0; r < 4; ++r) {
        int row = m * 16 + q * 4 + r;
        sT[row * 136 + col] = f2bf(fmaxf(acc[m][n][r] + bb, 0.f));
      }
  }
  __syncthreads();

  f32x4 acc2[4][2];
#pragma unroll
  for (int m = 0; m < 4; ++m)
#pragma unroll
    for (int n = 0; n < 2; ++n) acc2[m][n] = 0.f;
#pragma unroll
  for (int k0 = 0; k0 < 128; k0 += 32) {
    bf16x8 a[4];
#pragma unroll
    for (int m = 0; m < 4; ++m)
      a[m] = *(const bf16x8*)&sT[(m * 16 + ln) * 136 + k0 + q * 8];
#pragma unroll
    for (int n = 0; n < 2; ++n) {
      bf16x8 b = *(const bf16x8*)&W2[(nb + n * 16 + ln) * 128 + k0 + q * 8];
#pragma unroll
      for (int m = 0; m < 4; ++m) acc2[m][n] = MFMA16(a[m], b, acc2[m][n]);
    }
  }
#pragma unroll
  for (int n = 0; n < 2; ++n) {
    int col = nb + n * 16 + ln;
    float bb = b2[col];
#pragma unroll
    for (int m = 0; m < 4; ++m)
#pragma unroll
      for (int r = 0; r < 4; ++r) {
        int row = m * 16 + q * 4 + r;
        int node = nbase + row;
        if (node < NN) n2[(size_t)node * 128 + col] = f2bf(acc2[m][n][r] + bb);
      }
  }
}

// ---------------- fused edge kernel (one layer) ----------------
// K-chunked U (double-buffered), LDS ~53.5 KB -> 3 blocks/CU (12 waves)

__global__ __launch_bounds__(256, 3) void k_edge(
    const int* __restrict__ etype, const float* __restrict__ dist,
    const int* __restrict__ src, const int* __restrict__ dstv,
    const u16* __restrict__ T2, const u16* __restrict__ Dtab,
    const u16* __restrict__ We2b, const float* __restrict__ be2,
    const u16* __restrict__ Wcb, const float* __restrict__ bc,
    const u16* __restrict__ n2, float* __restrict__ h) {
  __shared__ __align__(16) u16 sC[2][64 * 136];  // U K-chunk buffers
  __shared__ __align__(16) u16 sP[64 * 136];
  __shared__ int sSrc[64], sDst[64], sT2o[64], sIdx[64];
  __shared__ float sFrac[64];

  const int tid = threadIdx.x;
  const int e0 = blockIdx.x * 64;
  if (tid < 64) {
    int e = e0 + tid;
    sSrc[tid] = src[e];
    sDst[tid] = dstv[e];
    sT2o[tid] = etype[e] * 448;
    float d = dist[e];
    float fi = d * ((float)GRID / 30.f);
    int ix = (int)fi;
    sIdx[tid] = ix * 448;
    sFrac[tid] = fi - (float)ix;
  }
  lds_barrier();

  const int lane = tid & 63, wave = tid >> 6;
  const int q = lane >> 4, ln = lane & 15;
  const int nb = wave * 32;

  f32x4 acc[4][2];
#pragma unroll
  for (int m = 0; m < 4; ++m)
#pragma unroll
    for (int n = 0; n < 2; ++n) acc[m][n] = 0.f;

  // 128-col chunk: 1024 bf16x8 units, 4/thread; cg = tid&15 fixed, e = tid>>4 + 16i
  auto prefetch128 = [&](int k0, bf16x8* plo, bf16x8* phi, bf16x8* pt2, float* pfr) {
    const int cg = tid & 15, eb = tid >> 4;
    const int col = k0 + cg * 8;
#pragma unroll
    for (int i = 0; i < 4; ++i) {
      int e = eb + i * 16;
      int off = sIdx[e] + col;
      plo[i] = *(const bf16x8*)&Dtab[off];
      phi[i] = *(const bf16x8*)&Dtab[off + 448];
      pt2[i] = *(const bf16x8*)&T2[sT2o[e] + col];
      pfr[i] = sFrac[e];
    }
  };
  auto store128 = [&](u16* buf, const bf16x8* plo, const bf16x8* phi,
                      const bf16x8* pt2, const float* pfr) {
    const int cg = tid & 15, eb = tid >> 4;
#pragma unroll
    for (int i = 0; i < 4; ++i) {
      int e = eb + i * 16;
      bf16x8 o;
#pragma unroll
      for (int j = 0; j < 8; ++j) {
        float l0 = (float)plo[i][j], h0 = (float)phi[i][j];
        float v = (float)pt2[i][j] + l0 + pfr[i] * (h0 - l0);
        o[j] = (__bf16)fmaxf(v, 0.f);
      }
      *(bf16x8*)&buf[e * 136 + cg * 8] = o;
    }
  };
  // 64-col tail chunk (cols 384..447): 512 units, 2/thread
  auto prefetch64 = [&](bf16x8* plo, bf16x8* phi, bf16x8* pt2, float* pfr) {
    const int cg = tid & 7, eb = tid >> 3;
    const int col = 384 + cg * 8;
#pragma unroll
    for (int i = 0; i < 2; ++i) {
      int e = eb + i * 32;
      int off = sIdx[e] + col;
      plo[i] = *(const bf16x8*)&Dtab[off];
      phi[i] = *(const bf16x8*)&Dtab[off + 448];
      pt2[i] = *(const bf16x8*)&T2[sT2o[e] + col];
      pfr[i] = sFrac[e];
    }
  };
  auto store64 = [&](u16* buf, const bf16x8* plo, const bf16x8* phi,
                     const bf16x8* pt2, const float* pfr) {
    const int cg = tid & 7, eb = tid >> 3;
#pragma unroll
    for (int i = 0; i < 2; ++i) {
      int e = eb + i * 32;
      bf16x8 o;
#pragma unroll
      for (int j = 0; j < 8; ++j) {
        float l0 = (float)plo[i][j], h0 = (float)phi[i][j];
        float v = (float)pt2[i][j] + l0 + pfr[i] * (h0 - l0);
        o[j] = (__bf16)fmaxf(v, 0.f);
      }
      *(bf16x8*)&buf[e * 136 + cg * 8] = o;
    }
  };
  auto mfma_chunk = [&](const u16* buf, int k0, int nk) {
    for (int kk = 0; kk < nk; ++kk) {
      bf16x8 a[4];
#pragma unroll
      for (int m = 0; m < 4; ++m)
        a[m] = *(const bf16x8*)&buf[(m * 16 + ln) * 136 + kk * 32 + q * 8];
#pragma unroll
      for (int n = 0; n < 2; ++n) {
        bf16x8 b = *(const bf16x8*)&We2b[(nb + n * 16 + ln) * 448 + k0 + kk * 32 + q * 8];
#pragma unroll
        for (int m = 0; m < 4; ++m) acc[m][n] = MFMA16(a[m], b, acc[m][n]);
      }
    }
  };

  // pipelined chunk schedule
  {
    bf16x8 plo[4], phi[4], pt2[4]; float pfr[4];
    prefetch128(0, plo, phi, pt2, pfr);
    store128(sC[0], plo, phi, pt2, pfr);
  }
  lds_barrier();
  {
    bf16x8 plo[4], phi[4], pt2[4]; float pfr[4];
    prefetch128(128, plo, phi, pt2, pfr);
    mfma_chunk(sC[0], 0, 4);
    store128(sC[1], plo, phi, pt2, pfr);
  }
  lds_barrier();
  {
    bf16x8 plo[4], phi[4], pt2[4]; float pfr[4];
    prefetch128(256, plo, phi, pt2, pfr);
    mfma_chunk(sC[1], 128, 4);
    store128(sC[0], plo, phi, pt2, pfr);
  }
  lds_barrier();
  {
    bf16x8 plo[2], phi[2], pt2[2]; float pfr[2];
    prefetch64(plo, phi, pt2, pfr);
    mfma_chunk(sC[0], 256, 4);
    store64(sC[1], plo, phi, pt2, pfr);
  }
  lds_barrier();

  // gather n2[src] early (consumed after final chunk's MFMA)
  unsigned short gr[4][4][2];
  {
    const int c0 = nb + ln, c1 = c0 + 16;
#pragma unroll
    for (int m = 0; m < 4; ++m)
#pragma unroll
      for (int r = 0; r < 4; ++r) {
        int s = sSrc[m * 16 + q * 4 + r];
        gr[m][r][0] = n2[(size_t)s * 128 + c0];
        gr[m][r][1] = n2[(size_t)s * 128 + c1];
      }
  }
  mfma_chunk(sC[1], 384, 2);

  // epilogue 2: P = (EE + be2) * n2[src]  -> sP
  {
    float be2v[2] = {be2[nb + ln], be2[nb + 16 + ln]};
#pragma unroll
    for (int n = 0; n < 2; ++n) {
      int col = nb + n * 16 + ln;
#pragma unroll
      for (int m = 0; m < 4; ++m)
#pragma unroll
        for (int r = 0; r < 4; ++r) {
          int row = m * 16 + q * 4 + r;
          float ee = acc[m][n][r] + be2v[n];
          float v = ee * bf2f(gr[m][r][n]);
          *(__bf16*)&sP[row * 136 + col] = (__bf16)v;
        }
    }
  }
  lds_barrier();

  // phase 3: m = tanh(P @ Wc^T + bc); h[dst] += m
  {
    f32x4 acc2[4][2];
#pragma unroll
    for (int m = 0; m < 4; ++m)
#pragma unroll
      for (int n = 0; n < 2; ++n) acc2[m][n] = 0.f;
#pragma unroll
    for (int k0 = 0; k0 < 128; k0 += 32) {
      bf16x8 a[4];
#pragma unroll
      for (int m = 0; m < 4; ++m)
        a[m] = *(const bf16x8*)&sP[(m * 16 + ln) * 136 + k0 + q * 8];
#pragma unroll
      for (int n = 0; n < 2; ++n) {
        bf16x8 b = *(const bf16x8*)&Wcb[(nb + n * 16 + ln) * 128 + k0 + q * 8];
#pragma unroll
        for (int m = 0; m < 4; ++m) acc2[m][n] = MFMA16(a[m], b, acc2[m][n]);
      }
    }
    float bcv[2] = {bc[nb + ln], bc[nb + 16 + ln]};
#pragma unroll
    for (int n = 0; n < 2; ++n) {
      int col = nb + n * 16 + ln;
#pragma unroll
      for (int m = 0; m < 4; ++m)
#pragma unroll
        for (int r = 0; r < 4; ++r) {
          int row = m * 16 + q * 4 + r;
          // Pade [3/2] tanh: inputs here are ~1e-3, err << bf16 ulp
          float x = acc2[m][n][r] + bcv[n];
          x = fminf(2.f, fmaxf(-2.f, x));
          float x2 = x * x;
          float t = x * (15.f + x2) * __builtin_amdgcn_rcpf(15.f + 6.f * x2);
          unsafeAtomicAdd(&h[(size_t)sDst[row] * 128 + col], t);
        }
    }
  }
}

// ---------------- readout ----------------

__global__ __launch_bounds__(256) void k_read(const float* __restrict__ h,
                                              const float* __restrict__ Wr1,
                                              const float* __restrict__ br1,
                                              const float* __restrict__ Wr2,
                                              const float* __restrict__ br2,
                                              const int* __restrict__ gid,
                                              float* __restrict__ out) {
  __shared__ __align__(16) u16 sH[64 * 136];
  __shared__ __align__(16) u16 sW[128 * 136];
  __shared__ float sR4[4][64];
  const int tid = threadIdx.x;
  const int nbase = blockIdx.x * 64;
  for (int i = tid; i < 64 * 128; i += 256) {
    int e = i >> 7, d = i & 127;
    int node = nbase + e;
    float v = (node < NN) ? h[(size_t)node * 128 + d] : 0.f;
    sH[e * 136 + d] = f2bf(v);
  }
  for (int i = tid; i < 128 * 128; i += 256) {
    int rr = i >> 7, d = i & 127;
    sW[rr * 136 + d] = f2bf(Wr1[i]);
  }
  __syncthreads();
  const int lane = tid & 63, wave = tid >> 6;
  const int q = lane >> 4, ln = lane & 15;
  const int nb = wave * 32;

  f32x4 acc[4][2];
#pragma unroll
  for (int m = 0; m < 4; ++m)
#pragma unroll
    for (int n = 0; n < 2; ++n) acc[m][n] = 0.f;
#pragma unroll
  for (int k0 = 0; k0 < 128; k0 += 32) {
    bf16x8 a[4];
#pragma unroll
    for (int m = 0; m < 4; ++m)
      a[m] = *(const bf16x8*)&sH[(m * 16 + ln) * 136 + k0 + q * 8];
#pragma unroll
    for (int n = 0; n < 2; ++n) {
      bf16x8 b = *(const bf16x8*)&sW[(nb + n * 16 + ln) * 136 + k0 + q * 8];
#pragma unroll
      for (int m = 0; m < 4; ++m) acc[m][n] = MFMA16(a[m], b, acc[m][n]);
    }
  }
#pragma unroll
  for (int m = 0; m < 4; ++m)
#pragma unroll
    for (int r = 0; r < 4; ++r) {
      float t = 0.f;
#pragma unroll
      for (int n = 0; n < 2; ++n) {
        int col = nb + n * 16 + ln;
        t += fmaxf(acc[m][n][r] + br1[col], 0.f) * Wr2[col];
      }
      t += __shfl_xor(t, 1);
      t += __shfl_xor(t, 2);
      t += __shfl_xor(t, 4);
      t += __shfl_xor(t, 8);
      if (ln == 0) sR4[wave][m * 16 + q * 4 + r] = t;
    }
  __syncthreads();
  if (tid < 64) {
    int node = nbase + tid;
    if (node < NN) {
      float s = sR4[0][tid] + sR4[1][tid] + sR4[2][tid] + sR4[3][tid] + br2[0];
      unsafeAtomicAdd(&out[gid[node]], s);
    }
  }
}

// ---------------- launch ----------------

extern "C" void kernel_launch(void* const* d_in, const int* in_sizes, int n_in,
                              void* d_out, int out_size, void* d_ws, size_t ws_size,
                              hipStream_t stream) {
  const int* Z = (const int*)d_in[0];
  const int* etype = (const int*)d_in[1];
  const float* dist = (const float*)d_in[2];
  const int* src = (const int*)d_in[3];
  const int* dst = (const int*)d_in[4];
  const int* gid = (const int*)d_in[5];
  const float* node_emb = (const float*)d_in[6];
  const float* edge_emb = (const float*)d_in[7];
  const float* Wn1 = (const float*)d_in[8];
  const float* bn1 = (const float*)d_in[9];
  const float* Wn2 = (const float*)d_in[10];
  const float* bn2 = (const float*)d_in[11];
  const float* We1 = (const float*)d_in[12];
  const float* be1 = (const float*)d_in[13];
  const float* We2 = (const float*)d_in[14];
  const float* be2 = (const float*)d_in[15];
  const float* Wc = (const float*)d_in[16];
  const float* bc = (const float*)d_in[17];
  const float* Wr1 = (const float*)d_in[18];
  const float* br1 = (const float*)d_in[19];
  const float* Wr2 = (const float*)d_in[20];
  const float* br2 = (const float*)d_in[21];
  float* out = (float*)d_out;

  char* ws = (char*)d_ws;
  float* h = (float*)(ws);                   // 51,200,000 B
  u16* n2 = (u16*)(ws + 51200000);           // 25,600,000 B
  u16* Rb = (u16*)(ws + 76800000);           //    860,160 B
  u16* We2b = (u16*)(ws + 77660160);         //    344,064 B
  u16* Wcb = (u16*)(ws + 78004224);          //     98,304 B
  u16* Wn1b = (u16*)(ws + 78102528);         //     98,304 B
  u16* Wn2b = (u16*)(ws + 78200832);         //     98,304 B
  u16* T2 = (u16*)(ws + 78299136);           //  1,075,200 B
  u16* Dtab = (u16*)(ws + 79374336);         //  5,507,712 B  (end 84,882,048)

  k_convert<<<192, 256, 0, stream>>>(Wn1, Wn1b, 49152);
  k_convert<<<192, 256, 0, stream>>>(Wn2, Wn2b, 49152);
  k_convert<<<192, 256, 0, stream>>>(Wc, Wcb, 49152);
  k_pad_we2<<<672, 256, 0, stream>>>(We2, We2b);
  k_pad_R<<<1680, 256, 0, stream>>>(We1, Rb);
  k_t2<<<2100, 256, 0, stream>>>(edge_emb, We1, be1, T2);
  k_dtab<<<3 * (GRID + 1), 256, 0, stream>>>(Rb, Dtab);
  k_hinit<<<12500, 256, 0, stream>>>(Z, node_emb, h);
  k_zero_out<<<8, 256, 0, stream>>>(out);

  for (int l = 0; l < 3; ++l) {
    k_node<<<1563, 256, 0, stream>>>(h, Wn1b + l * 16384, bn1 + l * 128,
                                     Wn2b + l * 16384, bn2 + l * 128, n2);
    k_edge<<<6250, 256, 0, stream>>>(etype, dist, src, dst,
                                     T2 + l * 179200, Dtab + (size_t)l * (GRID + 1) * 448,
                                     We2b + l * 57344, be2 + l * 128,
                                     Wcb + l * 16384, bc + l * 128, n2, h);
  }
  k_read<<<1563, 256, 0, stream>>>(h, Wr1, br1, Wr2, br2, gid, out);
}